// Round 3
// baseline (813.401 us; speedup 1.0000x reference)
//
#include <hip/hip_runtime.h>
#include <stdint.h>

#define B_ 2
#define H_ 16
#define S_ 2048
#define D_ 64
#define BM 128
#define BN 64
#define SCALE 0.125f

typedef __attribute__((ext_vector_type(4))) float f32x4;
typedef __attribute__((ext_vector_type(8))) short s16x8;

__device__ __forceinline__ unsigned short f2bf(float f) {
  union { float f; unsigned u; } x; x.f = f;
  unsigned u = x.u;
  u += 0x7fffu + ((u >> 16) & 1u);   // round-to-nearest-even
  return (unsigned short)(u >> 16);
}

// all LDS tiles have row stride 64 bf16 = 128 B; XOR-swizzle bits 4..6 by row&7
__device__ __forceinline__ int swz(int row, int cb) {
  return row * 128 + (cb ^ ((row & 7) << 4));
}

__device__ __forceinline__ void stage_64x64(const float* __restrict__ src, char* dst, int tid) {
  // 64x64 fp32 tile (contiguous 4096 floats) -> bf16 LDS, swizzled
  #pragma unroll
  for (int it = 0; it < 4; ++it) {
    int flat = it * 1024 + tid * 4;
    float4 f = *reinterpret_cast<const float4*>(src + flat);
    int r = flat >> 6, c = flat & 63;
    uint2 w;
    w.x = (unsigned)f2bf(f.x) | ((unsigned)f2bf(f.y) << 16);
    w.y = (unsigned)f2bf(f.z) | ((unsigned)f2bf(f.w) << 16);
    *reinterpret_cast<uint2*>(dst + swz(r, c * 2)) = w;
  }
}

__global__ __launch_bounds__(256) void attn_fused(
    const float* __restrict__ qg, const float* __restrict__ kg,
    const float* __restrict__ vg, const int* __restrict__ maskg,
    float* __restrict__ outg, float* __restrict__ pg) {
  __shared__ __align__(16) char smq[BM * 128];   // Q tile   [128][64] bf16
  __shared__ __align__(16) char smk[BN * 128];   // K tile   [64][64]  bf16
  __shared__ __align__(16) char smv[D_ * 128];   // V^T tile [64 d][64 k] bf16
  __shared__ __align__(16) char smp[BM * 128];   // P tile   [128][64] bf16
  __shared__ float lsum[BM];

  const int tid = threadIdx.x;
  const int lane15 = tid & 15;
  const int lhi = (tid & 63) >> 4;
  const int wid = tid >> 6;
  const int wbase = wid * 32;          // wave's 32-row strip of the q-tile
  const int bh = blockIdx.y;
  const int bb = bh >> 4;              // batch index (H=16)
  const int q0 = blockIdx.x * BM;

  // ---- stage Q tile (128x64) once ----
  {
    const float* src = qg + (size_t)(bh * S_ + q0) * D_;
    #pragma unroll
    for (int it = 0; it < 8; ++it) {
      int flat = it * 1024 + tid * 4;
      float4 f = *reinterpret_cast<const float4*>(src + flat);
      int r = flat >> 6, c = flat & 63;
      uint2 w;
      w.x = (unsigned)f2bf(f.x) | ((unsigned)f2bf(f.y) << 16);
      w.y = (unsigned)f2bf(f.z) | ((unsigned)f2bf(f.w) << 16);
      *reinterpret_cast<uint2*>(smq + swz(r, c * 2)) = w;
    }
  }
  __syncthreads();

  float lpart[2][4] = {{0.f,0.f,0.f,0.f},{0.f,0.f,0.f,0.f}};

  // ================= PASS A: row sums of exp =================
  for (int kb = 0; kb < S_; kb += BN) {
    stage_64x64(kg + (size_t)(bh * S_ + kb) * D_, smk, tid);
    __syncthreads();

    s16x8 aq[2][2];
    #pragma unroll
    for (int mt = 0; mt < 2; ++mt)
      #pragma unroll
      for (int kk = 0; kk < 2; ++kk)
        aq[mt][kk] = *reinterpret_cast<const s16x8*>(
            smq + swz(wbase + mt * 16 + lane15, kk * 64 + lhi * 16));

    #pragma unroll
    for (int nt = 0; nt < 4; ++nt) {
      s16x8 b0 = *reinterpret_cast<const s16x8*>(smk + swz(nt * 16 + lane15, lhi * 16));
      s16x8 b1 = *reinterpret_cast<const s16x8*>(smk + swz(nt * 16 + lane15, 64 + lhi * 16));
      #pragma unroll
      for (int mt = 0; mt < 2; ++mt) {
        f32x4 acc = {0.f, 0.f, 0.f, 0.f};
        acc = __builtin_amdgcn_mfma_f32_16x16x32_bf16(aq[mt][0], b0, acc, 0, 0, 0);
        acc = __builtin_amdgcn_mfma_f32_16x16x32_bf16(aq[mt][1], b1, acc, 0, 0, 0);
        int rg = q0 + wbase + mt * 16 + (lhi << 2);
        int cg = kb + nt * 16 + lane15;
        const int* mp = maskg + (size_t)(bb * S_ + rg) * S_ + cg;
        #pragma unroll
        for (int j = 0; j < 4; ++j) {
          float e = mp[j * S_] ? 0.f : __expf(acc[j] * SCALE);
          lpart[mt][j] += e;
        }
      }
    }
    __syncthreads();
  }

  // reduce row sums across the 16 lanes of each quarter-wave
  #pragma unroll
  for (int mt = 0; mt < 2; ++mt)
    #pragma unroll
    for (int j = 0; j < 4; ++j) {
      float s = lpart[mt][j];
      s += __shfl_xor(s, 8, 16);
      s += __shfl_xor(s, 4, 16);
      s += __shfl_xor(s, 2, 16);
      s += __shfl_xor(s, 1, 16);
      if (lane15 == 0) lsum[wbase + mt * 16 + (lhi << 2) + j] = s;
    }
  __syncthreads();

  float rinv[2][4];
  #pragma unroll
  for (int mt = 0; mt < 2; ++mt)
    #pragma unroll
    for (int j = 0; j < 4; ++j)
      rinv[mt][j] = 1.f / lsum[wbase + mt * 16 + (lhi << 2) + j];

  f32x4 oacc[2][4];
  #pragma unroll
  for (int mt = 0; mt < 2; ++mt)
    #pragma unroll
    for (int dt = 0; dt < 4; ++dt)
      oacc[mt][dt] = (f32x4){0.f, 0.f, 0.f, 0.f};

  // ================= PASS B: write p_attn, accumulate PV =================
  for (int kb = 0; kb < S_; kb += BN) {
    stage_64x64(kg + (size_t)(bh * S_ + kb) * D_, smk, tid);
    {  // stage V transposed: smv[d][k]
      const float* vs = vg + (size_t)(bh * S_ + kb) * D_;
      #pragma unroll
      for (int it = 0; it < 4; ++it) {
        int flat = it * 1024 + tid * 4;
        float4 f = *reinterpret_cast<const float4*>(vs + flat);
        int r = flat >> 6, c = flat & 63;   // r = k row, c = d col
        *reinterpret_cast<unsigned short*>(smv + swz(c + 0, r * 2)) = f2bf(f.x);
        *reinterpret_cast<unsigned short*>(smv + swz(c + 1, r * 2)) = f2bf(f.y);
        *reinterpret_cast<unsigned short*>(smv + swz(c + 2, r * 2)) = f2bf(f.z);
        *reinterpret_cast<unsigned short*>(smv + swz(c + 3, r * 2)) = f2bf(f.w);
      }
    }
    __syncthreads();

    s16x8 aq[2][2];
    #pragma unroll
    for (int mt = 0; mt < 2; ++mt)
      #pragma unroll
      for (int kk = 0; kk < 2; ++kk)
        aq[mt][kk] = *reinterpret_cast<const s16x8*>(
            smq + swz(wbase + mt * 16 + lane15, kk * 64 + lhi * 16));

    #pragma unroll
    for (int nt = 0; nt < 4; ++nt) {
      s16x8 b0 = *reinterpret_cast<const s16x8*>(smk + swz(nt * 16 + lane15, lhi * 16));
      s16x8 b1 = *reinterpret_cast<const s16x8*>(smk + swz(nt * 16 + lane15, 64 + lhi * 16));
      #pragma unroll
      for (int mt = 0; mt < 2; ++mt) {
        f32x4 acc = {0.f, 0.f, 0.f, 0.f};
        acc = __builtin_amdgcn_mfma_f32_16x16x32_bf16(aq[mt][0], b0, acc, 0, 0, 0);
        acc = __builtin_amdgcn_mfma_f32_16x16x32_bf16(aq[mt][1], b1, acc, 0, 0, 0);
        int rloc = wbase + mt * 16 + (lhi << 2);
        int rg = q0 + rloc;
        int cg = kb + nt * 16 + lane15;
        const int* mp = maskg + (size_t)(bb * S_ + rg) * S_ + cg;
        #pragma unroll
        for (int j = 0; j < 4; ++j) {
          float p = mp[j * S_] ? 0.f : __expf(acc[j] * SCALE) * rinv[mt][j];
          pg[(size_t)(bh * S_ + rg + j) * S_ + cg] = p;
          *reinterpret_cast<unsigned short*>(
              smp + swz(rloc + j, (nt * 16 + lane15) * 2)) = f2bf(p);
        }
      }
    }
    __syncthreads();   // P visible to everyone (cheap safety; own-wave rows anyway)

    s16x8 pa[2][2];
    #pragma unroll
    for (int mt = 0; mt < 2; ++mt)
      #pragma unroll
      for (int kk = 0; kk < 2; ++kk)
        pa[mt][kk] = *reinterpret_cast<const s16x8*>(
            smp + swz(wbase + mt * 16 + lane15, kk * 64 + lhi * 16));

    #pragma unroll
    for (int dt = 0; dt < 4; ++dt) {
      s16x8 v0 = *reinterpret_cast<const s16x8*>(smv + swz(dt * 16 + lane15, lhi * 16));
      s16x8 v1 = *reinterpret_cast<const s16x8*>(smv + swz(dt * 16 + lane15, 64 + lhi * 16));
      #pragma unroll
      for (int mt = 0; mt < 2; ++mt) {
        oacc[mt][dt] = __builtin_amdgcn_mfma_f32_16x16x32_bf16(pa[mt][0], v0, oacc[mt][dt], 0, 0, 0);
        oacc[mt][dt] = __builtin_amdgcn_mfma_f32_16x16x32_bf16(pa[mt][1], v1, oacc[mt][dt], 0, 0, 0);
      }
    }
    __syncthreads();   // protect smk/smv/smp before next staging
  }

  // ---- write out [bh][q][d] ----
  #pragma unroll
  for (int mt = 0; mt < 2; ++mt)
    #pragma unroll
    for (int dt = 0; dt < 4; ++dt)
      #pragma unroll
      for (int j = 0; j < 4; ++j)
        outg[(size_t)(bh * S_ + q0 + wbase + mt * 16 + (lhi << 2) + j) * D_ +
             dt * 16 + lane15] = oacc[mt][dt][j];
}

extern "C" void kernel_launch(void* const* d_in, const int* in_sizes, int n_in,
                              void* d_out, int out_size, void* d_ws, size_t ws_size,
                              hipStream_t stream) {
  (void)in_sizes; (void)n_in; (void)d_ws; (void)ws_size; (void)out_size;
  const float* q = (const float*)d_in[0];
  const float* k = (const float*)d_in[1];
  const float* v = (const float*)d_in[2];
  const int*   m = (const int*)d_in[3];
  float* out = (float*)d_out;
  float* p   = out + (size_t)B_ * H_ * S_ * D_;
  dim3 grid(S_ / BM, B_ * H_);
  attn_fused<<<grid, 256, 0, stream>>>(q, k, v, m, out, p);
}